// Round 1
// 1238.665 us; speedup vs baseline: 1.3522x; 1.3522x over previous
//
#include <hip/hip_runtime.h>
#include <hip/hip_fp16.h>

#define TSEQ  2048
#define BATCH 64
#define DIN   128
#define DH    256
#define WSTR  384   // W row stride = dimIn + dimH
#define NCH   (TSEQ / 16)

typedef __fp16 h2    __attribute__((ext_vector_type(2)));
typedef __fp16 f16x8 __attribute__((ext_vector_type(8)));
typedef float  f32x4 __attribute__((ext_vector_type(4)));

static __device__ __forceinline__ h2 bc_h2(unsigned int u) {
    return __builtin_bit_cast(h2, u);
}

// DPP quad_perm butterfly exchanges (pure VALU — no DS pipe, ~4 cyc latency).
// quad_perm ctrl = p0 | p1<<2 | p2<<4 | p3<<6
// xor1: [1,0,3,2] = 0xB1 ; xor2: [2,3,0,1] = 0x4E
#define DPP_XOR1(v) __builtin_bit_cast(float, \
    __builtin_amdgcn_mov_dpp(__builtin_bit_cast(int, (v)), 0xB1, 0xF, 0xF, true))
#define DPP_XOR2(v) __builtin_bit_cast(float, \
    __builtin_amdgcn_mov_dpp(__builtin_bit_cast(int, (v)), 0x4E, 0xF, 0xF, true))

// ---------------- Phase 1: xw = x @ Wx^T + b (f16 MFMA), into d_out ----------
// (unchanged from previous round — ~200 us, secondary)
__global__ __launch_bounds__(256) void xw_gemm(const float* __restrict__ x,
                                               const float* __restrict__ W,
                                               const float* __restrict__ bias,
                                               float* __restrict__ out) {
    __shared__ __align__(16) __fp16 af[64][136];

    const int tid  = threadIdx.x;
    const int lane = tid & 63;
    const int wv   = tid >> 6;
    const int row0 = blockIdx.x * 64;
    const int nlo  = lane & 15;
    const int quad = lane >> 4;

    {
        const int r  = tid >> 2;
        const int c0 = (tid & 3) * 32;
        const float4* xr = (const float4*)(x + (size_t)(row0 + r) * DIN) + (tid & 3) * 8;
#pragma unroll
        for (int i = 0; i < 4; ++i) {
            float4 f0 = xr[2 * i];
            float4 f1 = xr[2 * i + 1];
            f16x8 v;
            v[0]=(__fp16)f0.x; v[1]=(__fp16)f0.y; v[2]=(__fp16)f0.z; v[3]=(__fp16)f0.w;
            v[4]=(__fp16)f1.x; v[5]=(__fp16)f1.y; v[6]=(__fp16)f1.z; v[7]=(__fp16)f1.w;
            *(f16x8*)&af[r][c0 + i * 8] = v;
        }
    }

    f16x8 bfr[4][4];
#pragma unroll
    for (int n0 = 0; n0 < 4; ++n0) {
        const int n = wv * 64 + n0 * 16 + nlo;
        const float* wr = W + (size_t)n * WSTR;
#pragma unroll
        for (int kk = 0; kk < 4; ++kk) {
            const int k = kk * 32 + quad * 8;
            float4 f0 = *(const float4*)(wr + k);
            float4 f1 = *(const float4*)(wr + k + 4);
            f16x8 v;
            v[0]=(__fp16)f0.x; v[1]=(__fp16)f0.y; v[2]=(__fp16)f0.z; v[3]=(__fp16)f0.w;
            v[4]=(__fp16)f1.x; v[5]=(__fp16)f1.y; v[6]=(__fp16)f1.z; v[7]=(__fp16)f1.w;
            bfr[n0][kk] = v;
        }
    }
    __syncthreads();

    f32x4 acc[4][4];
#pragma unroll
    for (int m0 = 0; m0 < 4; ++m0)
#pragma unroll
        for (int n0 = 0; n0 < 4; ++n0) acc[m0][n0] = (f32x4)0.0f;

#pragma unroll
    for (int kk = 0; kk < 4; ++kk) {
#pragma unroll
        for (int m0 = 0; m0 < 4; ++m0) {
            f16x8 a = *(const f16x8*)&af[m0 * 16 + nlo][kk * 32 + quad * 8];
#pragma unroll
            for (int n0 = 0; n0 < 4; ++n0)
                acc[m0][n0] = __builtin_amdgcn_mfma_f32_16x16x32_f16(
                                  a, bfr[n0][kk], acc[m0][n0], 0, 0, 0);
        }
    }

#pragma unroll
    for (int n0 = 0; n0 < 4; ++n0) {
        const int col = wv * 64 + n0 * 16 + nlo;
        const float bn = bias[col];
#pragma unroll
        for (int m0 = 0; m0 < 4; ++m0)
#pragma unroll
            for (int r = 0; r < 4; ++r) {
                const int row = row0 + m0 * 16 + quad * 4 + r;
                out[(size_t)row * DH + col] = acc[m0][n0][r] + bn;
            }
    }
}

// ---------------- Phase 2: sequential scan, one block per batch ----------------
// v2 vs v1:
//  * butterfly via DPP quad_perm (VALU) instead of ds_swizzle (DS) — removes
//    two serial DS round-trips (~240 cyc) from every step's critical path
//  * w pinned to VGPRs (asm "+v") — v1's VGPR_Count=84 < 128 dwords of w
//    implies AGPR demotion => ~128 v_accvgpr_read per step of pure overhead
//  * raw s_barrier + explicit lgkmcnt(0) only (no vmcnt drain per step) =>
//    h stored straight to global fire-and-forget; xw prefetched 16 steps
//    ahead into registers (xwreg[16], statically indexed via full unroll) —
//    ring/xwb LDS and all chunk-boundary vmcnt(0) drains deleted.
// Per-step DS: 8x ds_read_b128 (hseg) + 1x ds_write_b16. One barrier/step.
__global__ __launch_bounds__(256, 1) void rnn_scan(const float* __restrict__ W,
                                                   const float* __restrict__ h0,
                                                   float* __restrict__ out) {
    __shared__ __align__(16) __fp16 hseg[2][4][72];   // ping-pong h, pad 64->72

    const int tid = threadIdx.x;
    const int b   = blockIdx.x;
    const int q   = tid & 3;
    const int g   = tid >> 2;
    const bool b0 = (q & 1) != 0;
    const bool b1 = (q >> 1) != 0;

    // Wh f16: rows 4g..4g+3, k in [64q, 64q+64)  -> 128 dwords
    h2 w[4][32];
#pragma unroll
    for (int o = 0; o < 4; ++o) {
        const float* wr = W + (size_t)(4 * g + o) * WSTR + DIN + 64 * q;
#pragma unroll
        for (int i = 0; i < 16; ++i) {
            float4 f = *(const float4*)(wr + 4 * i);
            w[o][2 * i]     = h2{(__fp16)f.x, (__fp16)f.y};
            w[o][2 * i + 1] = h2{(__fp16)f.z, (__fp16)f.w};
        }
    }
    // pin w into VGPRs — block the allocator's AGPR-copy heuristic
    // (v_dot2_f32_f16 can't read AGPRs; demotion costs an accvgpr_read per use)
#pragma unroll
    for (int o = 0; o < 4; ++o)
#pragma unroll
        for (int i = 0; i < 32; ++i)
            asm volatile("" : "+v"(w[o][i]));

    hseg[0][tid >> 6][tid & 63] = (__fp16)h0[(size_t)b * DH + tid];

    const float* gsrc = out + (size_t)b * TSEQ * DH + tid;  // xw column tid
    float*       gdst = out + (size_t)b * TSEQ * DH + tid;  // h   column tid

    // prologue: xw chunk 0 -> registers
    float xwreg[16];
#pragma unroll
    for (int s = 0; s < 16; ++s) xwreg[s] = gsrc[(size_t)s * DH];

    asm volatile("s_waitcnt lgkmcnt(0)\n\ts_barrier" ::: "memory");

#pragma unroll 1
    for (int c = 0; c < NCH; ++c) {
        // next chunk base (clamped to a valid address on the last chunk;
        // prefetched values are then unused)
        const float* gnext = gsrc + (size_t)(c + 1 < NCH ? c + 1 : 0) * (16 * DH);
        float*       gout  = gdst + (size_t)c * (16 * DH);

#pragma unroll
        for (int s = 0; s < 16; ++s) {
            const float xw_s = xwreg[s];
            xwreg[s] = gnext[(size_t)s * DH];   // prefetch: used 16 steps later,
                                                // compiler inserts the exact vmcnt
            const int p = s & 1;                // ping-pong parity (chunk len even)
            const uint4* hp = (const uint4*)&hseg[p][q][0];

            float P0 = 0.f, P1 = 0.f, P2 = 0.f, P3 = 0.f;
#pragma unroll
            for (int i = 0; i < 8; ++i) {
                uint4 v = hp[i];
                h2 ha = bc_h2(v.x), hb = bc_h2(v.y), hc = bc_h2(v.z), hd = bc_h2(v.w);
                P0 = __builtin_amdgcn_fdot2(w[0][4*i], ha, P0, false);
                P1 = __builtin_amdgcn_fdot2(w[1][4*i], ha, P1, false);
                P2 = __builtin_amdgcn_fdot2(w[2][4*i], ha, P2, false);
                P3 = __builtin_amdgcn_fdot2(w[3][4*i], ha, P3, false);
                P0 = __builtin_amdgcn_fdot2(w[0][4*i+1], hb, P0, false);
                P1 = __builtin_amdgcn_fdot2(w[1][4*i+1], hb, P1, false);
                P2 = __builtin_amdgcn_fdot2(w[2][4*i+1], hb, P2, false);
                P3 = __builtin_amdgcn_fdot2(w[3][4*i+1], hb, P3, false);
                P0 = __builtin_amdgcn_fdot2(w[0][4*i+2], hc, P0, false);
                P1 = __builtin_amdgcn_fdot2(w[1][4*i+2], hc, P1, false);
                P2 = __builtin_amdgcn_fdot2(w[2][4*i+2], hc, P2, false);
                P3 = __builtin_amdgcn_fdot2(w[3][4*i+2], hc, P3, false);
                P0 = __builtin_amdgcn_fdot2(w[0][4*i+3], hd, P0, false);
                P1 = __builtin_amdgcn_fdot2(w[1][4*i+3], hd, P1, false);
                P2 = __builtin_amdgcn_fdot2(w[2][4*i+3], hd, P2, false);
                P3 = __builtin_amdgcn_fdot2(w[3][4*i+3], hd, P3, false);
            }

            // butterfly over q via DPP (same pairings as the old ds_swizzle):
            // round 1 (xor 1) keeps o with o&1==q&1
            float sendA = b0 ? P0 : P1;
            float sendB = b0 ? P2 : P3;
            float keepA = b0 ? P1 : P0;
            float keepB = b0 ? P3 : P2;
            float S0 = keepA + DPP_XOR1(sendA);   // o = b0
            float S1 = keepB + DPP_XOR1(sendB);   // o = b0+2
            // round 2 (xor 2) keeps o == q
            float send2 = b1 ? S0 : S1;
            float keep2 = b1 ? S1 : S0;
            float dot = keep2 + DPP_XOR2(send2);

            float pre = xw_s + dot;
            // tanh(x) = 1 - 2/(e^(2x)+1)
            float e  = __expf(2.0f * pre);
            float hn = 1.0f - 2.0f * __builtin_amdgcn_rcpf(e + 1.0f);

            hseg[p ^ 1][tid >> 6][tid & 63] = (__fp16)hn;   // earliest issue
            gout[(size_t)s * DH] = hn;                      // fire-and-forget

            // barrier WITHOUT vmcnt drain: only LDS must be visible.
            // in-flight global stores/prefetch loads stay outstanding.
            asm volatile("s_waitcnt lgkmcnt(0)\n\ts_barrier" ::: "memory");
        }
    }
}

extern "C" void kernel_launch(void* const* d_in, const int* in_sizes, int n_in,
                              void* d_out, int out_size, void* d_ws, size_t ws_size,
                              hipStream_t stream) {
    const float* x    = (const float*)d_in[0];
    const float* h0   = (const float*)d_in[1];
    const float* W    = (const float*)d_in[2];
    const float* bias = (const float*)d_in[3];
    float* out = (float*)d_out;

    xw_gemm<<<BATCH * TSEQ / 64, 256, 0, stream>>>(x, W, bias, out);
    rnn_scan<<<BATCH, 256, 0, stream>>>(W, h0, out);
}

// Round 2
// 994.662 us; speedup vs baseline: 1.6839x; 1.2453x over previous
//
#include <hip/hip_runtime.h>
#include <hip/hip_fp16.h>

#define TSEQ  2048
#define BATCH 64
#define DIN   128
#define DH    256
#define WSTR  384   // W row stride = dimIn + dimH
#define NCH   (TSEQ / 16)

typedef __fp16 h2    __attribute__((ext_vector_type(2)));
typedef __fp16 f16x8 __attribute__((ext_vector_type(8)));
typedef float  f32x4 __attribute__((ext_vector_type(4)));

static __device__ __forceinline__ h2 bc_h2(unsigned int u) {
    return __builtin_bit_cast(h2, u);
}

// Pure-VALU cross-lane exchanges (no DS pipe):
// quad_perm xor1: [1,0,3,2] = 0xB1 ; xor2: [2,3,0,1] = 0x4E
// xor8: row_ror:8 (0x128) — within a 16-lane row, (i+8)%16 == i^8
#define DPP_XOR1(v) __builtin_bit_cast(float, \
    __builtin_amdgcn_mov_dpp(__builtin_bit_cast(int, (v)), 0xB1, 0xF, 0xF, true))
#define DPP_XOR2(v) __builtin_bit_cast(float, \
    __builtin_amdgcn_mov_dpp(__builtin_bit_cast(int, (v)), 0x4E, 0xF, 0xF, true))
#define DPP_XOR8(v) __builtin_bit_cast(float, \
    __builtin_amdgcn_mov_dpp(__builtin_bit_cast(int, (v)), 0x128, 0xF, 0xF, true))

// ---------------- Phase 1: xw = x @ Wx^T + b (f16 MFMA), into d_out ----------
// (unchanged — ~200 us, tackled after the scan stops dominating)
__global__ __launch_bounds__(256) void xw_gemm(const float* __restrict__ x,
                                               const float* __restrict__ W,
                                               const float* __restrict__ bias,
                                               float* __restrict__ out) {
    __shared__ __align__(16) __fp16 af[64][136];

    const int tid  = threadIdx.x;
    const int lane = tid & 63;
    const int wv   = tid >> 6;
    const int row0 = blockIdx.x * 64;
    const int nlo  = lane & 15;
    const int quad = lane >> 4;

    {
        const int r  = tid >> 2;
        const int c0 = (tid & 3) * 32;
        const float4* xr = (const float4*)(x + (size_t)(row0 + r) * DIN) + (tid & 3) * 8;
#pragma unroll
        for (int i = 0; i < 4; ++i) {
            float4 f0 = xr[2 * i];
            float4 f1 = xr[2 * i + 1];
            f16x8 v;
            v[0]=(__fp16)f0.x; v[1]=(__fp16)f0.y; v[2]=(__fp16)f0.z; v[3]=(__fp16)f0.w;
            v[4]=(__fp16)f1.x; v[5]=(__fp16)f1.y; v[6]=(__fp16)f1.z; v[7]=(__fp16)f1.w;
            *(f16x8*)&af[r][c0 + i * 8] = v;
        }
    }

    f16x8 bfr[4][4];
#pragma unroll
    for (int n0 = 0; n0 < 4; ++n0) {
        const int n = wv * 64 + n0 * 16 + nlo;
        const float* wr = W + (size_t)n * WSTR;
#pragma unroll
        for (int kk = 0; kk < 4; ++kk) {
            const int k = kk * 32 + quad * 8;
            float4 f0 = *(const float4*)(wr + k);
            float4 f1 = *(const float4*)(wr + k + 4);
            f16x8 v;
            v[0]=(__fp16)f0.x; v[1]=(__fp16)f0.y; v[2]=(__fp16)f0.z; v[3]=(__fp16)f0.w;
            v[4]=(__fp16)f1.x; v[5]=(__fp16)f1.y; v[6]=(__fp16)f1.z; v[7]=(__fp16)f1.w;
            bfr[n0][kk] = v;
        }
    }
    __syncthreads();

    f32x4 acc[4][4];
#pragma unroll
    for (int m0 = 0; m0 < 4; ++m0)
#pragma unroll
        for (int n0 = 0; n0 < 4; ++n0) acc[m0][n0] = (f32x4)0.0f;

#pragma unroll
    for (int kk = 0; kk < 4; ++kk) {
#pragma unroll
        for (int m0 = 0; m0 < 4; ++m0) {
            f16x8 a = *(const f16x8*)&af[m0 * 16 + nlo][kk * 32 + quad * 8];
#pragma unroll
            for (int n0 = 0; n0 < 4; ++n0)
                acc[m0][n0] = __builtin_amdgcn_mfma_f32_16x16x32_f16(
                                  a, bfr[n0][kk], acc[m0][n0], 0, 0, 0);
        }
    }

#pragma unroll
    for (int n0 = 0; n0 < 4; ++n0) {
        const int col = wv * 64 + n0 * 16 + nlo;
        const float bn = bias[col];
#pragma unroll
        for (int m0 = 0; m0 < 4; ++m0)
#pragma unroll
            for (int r = 0; r < 4; ++r) {
                const int row = row0 + m0 * 16 + quad * 4 + r;
                out[(size_t)row * DH + col] = acc[m0][n0][r] + bn;
            }
    }
}

// ---------------- Phase 2: sequential scan, one block per batch ----------------
// v3 vs v2:
//  * 8 k-segments of 32 (was 4 of 64): per-thread h read 128B -> 64B, per-CU
//    LDS return traffic 32KB -> 16KB/step (pipe time halves). Extra butterfly
//    round uses DPP row_ror:8 (lane^8) — still zero DS-pipe ops.
//  * relative partial indexing: thread t computes partials for outputs
//    t ^ rho(r), rho(r) = (r&3)|((r&4)<<1) in span{1,2,8}. Send/keep becomes
//    index parity => butterfly is 7 adds + 7 DPP movs, ZERO cndmask.
//  * h layout [8 segs][40 f16] (80B stride): bank starts 20*sig mod 32 =
//    {0,20,8,28,16,4,24,12} — perfect 32-bank partition, zero-conflict b128.
__global__ __launch_bounds__(256, 1) void rnn_scan(const float* __restrict__ W,
                                                   const float* __restrict__ h0,
                                                   float* __restrict__ out) {
    __shared__ __align__(16) __fp16 hseg[2][8][40];   // ping-pong h, 80B/seg

    const int tid = threadIdx.x;
    const int b   = blockIdx.x;
    const int sig = (tid & 3) | ((tid & 8) >> 1);     // segment from lane bits {0,1,3}

    // Wh f16: rows tid^rho(r), k in [32*sig, 32*sig+32)  -> 128 VGPRs
    h2 w[8][16];
#pragma unroll
    for (int r = 0; r < 8; ++r) {
        const int rho = (r & 3) | ((r & 4) << 1);     // {0,1,2,3,8,9,10,11}
        const float* wr = W + (size_t)(tid ^ rho) * WSTR + DIN + 32 * sig;
#pragma unroll
        for (int j = 0; j < 8; ++j) {
            float4 f = *(const float4*)(wr + 4 * j);
            w[r][2 * j]     = h2{(__fp16)f.x, (__fp16)f.y};
            w[r][2 * j + 1] = h2{(__fp16)f.z, (__fp16)f.w};
        }
    }
    // pin w into VGPRs (v_dot2 can't read AGPRs; demotion = accvgpr_read per use)
#pragma unroll
    for (int r = 0; r < 8; ++r)
#pragma unroll
        for (int i = 0; i < 16; ++i)
            asm volatile("" : "+v"(w[r][i]));

    hseg[0][tid >> 5][tid & 31] = (__fp16)h0[(size_t)b * DH + tid];

    const float* gsrc = out + (size_t)b * TSEQ * DH + tid;  // xw column tid
    float*       gdst = out + (size_t)b * TSEQ * DH + tid;  // h   column tid

    // prologue: xw chunk 0 -> registers
    float xwreg[16];
#pragma unroll
    for (int s = 0; s < 16; ++s) xwreg[s] = gsrc[(size_t)s * DH];

    asm volatile("s_waitcnt lgkmcnt(0)\n\ts_barrier" ::: "memory");

#pragma unroll 1
    for (int c = 0; c < NCH; ++c) {
        const float* gnext = gsrc + (size_t)(c + 1 < NCH ? c + 1 : 0) * (16 * DH);
        float*       gout  = gdst + (size_t)c * (16 * DH);

#pragma unroll
        for (int s = 0; s < 16; ++s) {
            const float xw_s = xwreg[s];
            xwreg[s] = gnext[(size_t)s * DH];   // prefetch, used 16 steps later
            const int p = s & 1;                // ping-pong parity (compile-time)
            const uint4* hp = (const uint4*)&hseg[p][sig][0];

            float P[8];
#pragma unroll
            for (int r = 0; r < 8; ++r) P[r] = 0.f;
#pragma unroll
            for (int i4 = 0; i4 < 4; ++i4) {
                uint4 v = hp[i4];
                h2 ha = bc_h2(v.x), hb = bc_h2(v.y), hc = bc_h2(v.z), hd = bc_h2(v.w);
#pragma unroll
                for (int r = 0; r < 8; ++r) {
                    P[r] = __builtin_amdgcn_fdot2(w[r][4*i4+0], ha, P[r], false);
                    P[r] = __builtin_amdgcn_fdot2(w[r][4*i4+1], hb, P[r], false);
                    P[r] = __builtin_amdgcn_fdot2(w[r][4*i4+2], hc, P[r], false);
                    P[r] = __builtin_amdgcn_fdot2(w[r][4*i4+3], hd, P[r], false);
                }
            }

            // butterfly: static pairing, no selects.
            // After round k, reg j holds output t ^ rho(2^k * j) partial-sums.
            float S0 = P[0] + DPP_XOR1(P[1]);
            float S1 = P[2] + DPP_XOR1(P[3]);
            float S2 = P[4] + DPP_XOR1(P[5]);
            float S3 = P[6] + DPP_XOR1(P[7]);
            float T0 = S0 + DPP_XOR2(S1);
            float T1 = S2 + DPP_XOR2(S3);
            float dot = T0 + DPP_XOR8(T1);

            float pre = xw_s + dot;
            // tanh(x) = 1 - 2/(e^(2x)+1)
            float e  = __expf(2.0f * pre);
            float hn = 1.0f - 2.0f * __builtin_amdgcn_rcpf(e + 1.0f);

            hseg[p ^ 1][tid >> 5][tid & 31] = (__fp16)hn;   // earliest issue
            gout[(size_t)s * DH] = hn;                      // fire-and-forget

            // barrier WITHOUT vmcnt drain: only LDS must be visible.
            asm volatile("s_waitcnt lgkmcnt(0)\n\ts_barrier" ::: "memory");
        }
    }
}

extern "C" void kernel_launch(void* const* d_in, const int* in_sizes, int n_in,
                              void* d_out, int out_size, void* d_ws, size_t ws_size,
                              hipStream_t stream) {
    const float* x    = (const float*)d_in[0];
    const float* h0   = (const float*)d_in[1];
    const float* W    = (const float*)d_in[2];
    const float* bias = (const float*)d_in[3];
    float* out = (float*)d_out;

    xw_gemm<<<BATCH * TSEQ / 64, 256, 0, stream>>>(x, W, bias, out);
    rnn_scan<<<BATCH, 256, 0, stream>>>(W, h0, out);
}